// Round 3
// baseline (186.034 us; speedup 1.0000x reference)
//
#include <hip/hip_runtime.h>
#include <hip/hip_bf16.h>

// AdaptiveGraphNetwork via MFMA 16x16x32 bf16. B=4096, N=64, D=32, H=64.
//
// v3: occupancy restructure. v2's counters showed MfmaUtil 0.76% / VALU 2.2% /
// HBM 4.5% / Occupancy 1.56% -- latency-bound with only 2 blocks/CU (LDS 57KB).
// Now 1 batch per iteration: LDS 28672 B (sH 128x72 + sMB 128x40), NBATCH=4,
// grid=1024 WGs, __launch_bounds__(256,4) -> 4 blocks/CU = 16 waves/CU (2x).
//
// Kept from v2 (neutral on time but fewer instructions, correct):
//  * Swapped-operand MFMA in phases A/B/C (h^T = W^T@x^T): C-frag holds 4
//    contiguous feature values -> packed ds_write_b64.
//  * A->B and C->D are wave-local: lgkmcnt fence instead of s_barrier.
//  * Cross-wave barriers drain lgkmcnt only (no vmcnt).
//
// Fragment maps (m89/m91-verified): A[m=lane&15][k=quad*8+j],
// B[k=quad*8+j][n=lane&15], C/D[row=quad*4+reg][col=lane&15].
// A-frag of W^T == B-frag of W, so one set of weight fragments serves both
// the swapped and normal orientations.

typedef __bf16 bf16x8 __attribute__((ext_vector_type(8)));
typedef float  f32x4  __attribute__((ext_vector_type(4)));
typedef unsigned short u16;

#define NBATCH 4          // batches per WG (1 per iteration)
#define ITERS  NBATCH
#define HS  72   // sH row stride in u16 (144 B, 16B-aligned)
#define MBS 40   // sMB row stride in u16 (80 B, 16B-aligned)

__device__ __forceinline__ u16 f2b(float f) { return __builtin_bit_cast(u16, (__bf16)f); }
__device__ __forceinline__ f32x4 MFMA(bf16x8 a, bf16x8 b, f32x4 c) {
    return __builtin_amdgcn_mfma_f32_16x16x32_bf16(a, b, c, 0, 0, 0);
}
__device__ __forceinline__ bf16x8 pack8(float4 a, float4 b) {
    bf16x8 r = {(__bf16)a.x, (__bf16)a.y, (__bf16)a.z, (__bf16)a.w,
                (__bf16)b.x, (__bf16)b.y, (__bf16)b.z, (__bf16)b.w};
    return r;
}
// relu(acc + bias) for the 4 C^T rows of one lane, packed as 4 bf16.
__device__ __forceinline__ uint2 relu_pack4(f32x4 acc, f32x4 bias) {
    uint2 o;
    o.x = (unsigned)f2b(fmaxf(acc[0] + bias[0], 0.f)) |
          ((unsigned)f2b(fmaxf(acc[1] + bias[1], 0.f)) << 16);
    o.y = (unsigned)f2b(fmaxf(acc[2] + bias[2], 0.f)) |
          ((unsigned)f2b(fmaxf(acc[3] + bias[3], 0.f)) << 16);
    return o;
}
// Wave-local LDS producer->consumer fence (same-wave ds ops are in-order).
__device__ __forceinline__ void wave_lds_fence() {
    asm volatile("s_waitcnt lgkmcnt(0)" ::: "memory");
}
// Cross-wave barrier draining LDS only (no cross-wave global deps).
__device__ __forceinline__ void barrier_lds() {
    asm volatile("s_waitcnt lgkmcnt(0)" ::: "memory");
    __builtin_amdgcn_s_barrier();
    asm volatile("" ::: "memory");
}

__global__ __launch_bounds__(256, 4)
void agn_mfma(const float* __restrict__ x, const float* __restrict__ Wm1,
              const float* __restrict__ bm1, const float* __restrict__ Wm2,
              const float* __restrict__ bm2, const float* __restrict__ Wu1,
              const float* __restrict__ bu1, const float* __restrict__ Wu2,
              const float* __restrict__ bu2, const float* __restrict__ rw_p,
              float* __restrict__ out)
{
    __shared__ __align__(16) u16 sH[128 * HS];    // rows 0..127 edge-h; rows 0..63 reused as hu
    __shared__ __align__(16) u16 sMB[128 * MBS];  // rows 0..127 edge messages

    const int t = threadIdx.x;
    const int w = t >> 6;
    const int lane = t & 63;
    const int ln = lane & 15;
    const int q  = lane >> 4;

    // ---------------- weight fragments (once per WG) ----------------
    bf16x8 B1a[4], B1b[4], B2[2][2], B3[2][4], B4[2][2];
#pragma unroll
    for (int nt = 0; nt < 4; ++nt)
#pragma unroll
        for (int j = 0; j < 8; ++j) {
            B1a[nt][j] = (__bf16)Wm1[(q * 8 + j) * 64 + nt * 16 + ln];
            B1b[nt][j] = (__bf16)Wm1[(32 + q * 8 + j) * 64 + nt * 16 + ln];
        }
#pragma unroll
    for (int s = 0; s < 2; ++s)
#pragma unroll
        for (int nt = 0; nt < 2; ++nt)
#pragma unroll
            for (int j = 0; j < 8; ++j)
                B2[s][nt][j] = (__bf16)Wm2[(s * 32 + q * 8 + j) * 32 + nt * 16 + ln];
#pragma unroll
    for (int s = 0; s < 2; ++s)
#pragma unroll
        for (int nt = 0; nt < 4; ++nt)
#pragma unroll
            for (int j = 0; j < 8; ++j)
                B3[s][nt][j] = (__bf16)Wu1[(s * 32 + q * 8 + j) * 64 + nt * 16 + ln];
#pragma unroll
    for (int s = 0; s < 2; ++s)
#pragma unroll
        for (int nt = 0; nt < 2; ++nt)
#pragma unroll
            for (int j = 0; j < 8; ++j)
                B4[s][nt][j] = (__bf16)Wu2[(s * 32 + q * 8 + j) * 32 + nt * 16 + ln];

    // Biases. Swapped phases (A/B/C) index by C^T row = tile*16 + q*4 + r.
    f32x4 bm1s[4], bu1s[4], bm2s[2];
#pragma unroll
    for (int ht = 0; ht < 4; ++ht)
#pragma unroll
        for (int r = 0; r < 4; ++r) {
            bm1s[ht][r] = bm1[ht * 16 + q * 4 + r];
            bu1s[ht][r] = bu1[ht * 16 + q * 4 + r];
        }
#pragma unroll
    for (int s = 0; s < 2; ++s)
#pragma unroll
        for (int r = 0; r < 4; ++r)
            bm2s[s][r] = bm2[s * 16 + q * 4 + r];
    float bu2v[2];
#pragma unroll
    for (int nt = 0; nt < 2; ++nt) bu2v[nt] = bu2[nt * 16 + ln];
    const float rw = rw_p[0];
    const float om = 1.f - rw;

    const size_t base = (size_t)blockIdx.x * (NBATCH * 64 * 32);

    for (int it = 0; it < ITERS; ++it) {
        const float* xit = x + base + (size_t)it * (64 * 32);
        float*       oit = out + base + (size_t)it * (64 * 32);

        // ===== Phase A (swapped): h^T = Wm1t^T@xd^T + Wm1b^T@xs^T, relu =====
        // Wave w covers edge rows [32w, 32w+32). Packed b64 -> sH[edge][hf].
        {
            float4 xd[2][2], xsv[2][2];
#pragma unroll
            for (int m = 0; m < 2; ++m) {
                const int erow = (2 * w + m) * 16 + ln;
                int e = erow;
                if (e >= 126) e = 0;  // pad rows, never read downstream
                const int dst  = (e < 63) ? e : e - 62;
                const int srcn = (e < 63) ? e + 1 : e - 63;
                const float* pd = xit + dst * 32 + q * 8;
                const float* ps = xit + srcn * 32 + q * 8;
                xd[m][0] = *(const float4*)pd;  xd[m][1] = *(const float4*)(pd + 4);
                xsv[m][0] = *(const float4*)ps; xsv[m][1] = *(const float4*)(ps + 4);
            }
#pragma unroll
            for (int m = 0; m < 2; ++m) {
                const int erow = (2 * w + m) * 16 + ln;
                bf16x8 Ad = pack8(xd[m][0], xd[m][1]);
                bf16x8 As = pack8(xsv[m][0], xsv[m][1]);
                u16* rowp = &sH[erow * HS];
#pragma unroll
                for (int ht = 0; ht < 4; ++ht) {
                    f32x4 acc = {0.f, 0.f, 0.f, 0.f};
                    acc = MFMA(B1a[ht], Ad, acc);
                    acc = MFMA(B1b[ht], As, acc);
                    *(uint2*)&rowp[ht * 16 + q * 4] = relu_pack4(acc, bm1s[ht]);
                }
            }
        }
        wave_lds_fence();  // A->B wave-local (rows [32w,32w+32))

        // ===== Phase B (swapped): msgb^T = Wm2^T @ h^T, relu =====
#pragma unroll
        for (int m = 0; m < 2; ++m) {
            const int row = (2 * w + m) * 16 + ln;
            bf16x8 A0 = __builtin_bit_cast(bf16x8, *(const uint4*)&sH[row * HS + q * 8]);
            bf16x8 A1 = __builtin_bit_cast(bf16x8, *(const uint4*)&sH[row * HS + 32 + q * 8]);
#pragma unroll
            for (int s = 0; s < 2; ++s) {
                f32x4 acc = {0.f, 0.f, 0.f, 0.f};
                acc = MFMA(B2[0][s], A0, acc);
                acc = MFMA(B2[1][s], A1, acc);
                *(uint2*)&sMB[row * MBS + s * 16 + q * 4] = relu_pack4(acc, bm2s[s]);
            }
        }
        barrier_lds();  // sMB scatter in C is cross-wave

        // ===== Phase C (swapped): hu^T = Wu1^T @ [x | scatter(msgb)]^T, relu =====
        {
            const int row = w * 16 + ln;   // node 0..63
            const float* p = xit + row * 32 + q * 8;
            float4 a0 = *(const float4*)p;
            float4 a1 = *(const float4*)(p + 4);
            bf16x8 A0 = pack8(a0, a1);
            float mv[8] = {0.f, 0.f, 0.f, 0.f, 0.f, 0.f, 0.f, 0.f};
            if (row < 63) {  // forward edge row -> dst row
                uint4 u = *(const uint4*)&sMB[row * MBS + q * 8];
                const unsigned* pu = (const unsigned*)&u;
#pragma unroll
                for (int h = 0; h < 4; ++h) {
                    mv[2 * h]     += __uint_as_float(pu[h] << 16);
                    mv[2 * h + 1] += __uint_as_float(pu[h] & 0xFFFF0000u);
                }
            }
            if (row > 0) {   // backward edge 62+row -> dst row
                uint4 u = *(const uint4*)&sMB[(62 + row) * MBS + q * 8];
                const unsigned* pu = (const unsigned*)&u;
#pragma unroll
                for (int h = 0; h < 4; ++h) {
                    mv[2 * h]     += __uint_as_float(pu[h] << 16);
                    mv[2 * h + 1] += __uint_as_float(pu[h] & 0xFFFF0000u);
                }
            }
            bf16x8 A1;
#pragma unroll
            for (int j = 0; j < 8; ++j) A1[j] = (__bf16)mv[j];
#pragma unroll
            for (int ht = 0; ht < 4; ++ht) {
                f32x4 acc = {0.f, 0.f, 0.f, 0.f};
                acc = MFMA(B3[0][ht], A0, acc);
                acc = MFMA(B3[1][ht], A1, acc);
                *(uint2*)&sH[row * HS + ht * 16 + q * 4] = relu_pack4(acc, bu1s[ht]);
            }
        }
        wave_lds_fence();  // C->D wave-local (rows [16w,16w+16))

        // ===== Phase D (normal): out = rw*(hu @ Wu2 + bu2) + (1-rw)*x =====
        {
            const int arow = w * 16 + ln;
            bf16x8 A0 = __builtin_bit_cast(bf16x8, *(const uint4*)&sH[arow * HS + q * 8]);
            bf16x8 A1 = __builtin_bit_cast(bf16x8, *(const uint4*)&sH[arow * HS + 32 + q * 8]);
#pragma unroll
            for (int nt = 0; nt < 2; ++nt) {
                f32x4 acc = {0.f, 0.f, 0.f, 0.f};
                acc = MFMA(A0, B4[0][nt], acc);
                acc = MFMA(A1, B4[1][nt], acc);
                const int rb = w * 16 + q * 4;
                const int c  = nt * 16 + ln;
#pragma unroll
                for (int r = 0; r < 4; ++r) {
                    const int off = (rb + r) * 32 + c;
                    oit[off] = rw * (acc[r] + bu2v[nt]) + om * xit[off];
                }
            }
        }
        barrier_lds();  // sH/sMB consumed before next iter overwrites
    }
}

extern "C" void kernel_launch(void* const* d_in, const int* in_sizes, int n_in,
                              void* d_out, int out_size, void* d_ws, size_t ws_size,
                              hipStream_t stream) {
    const float* x   = (const float*)d_in[0];
    const float* Wm1 = (const float*)d_in[1];
    const float* bm1 = (const float*)d_in[2];
    const float* Wm2 = (const float*)d_in[3];
    const float* bm2 = (const float*)d_in[4];
    const float* Wu1 = (const float*)d_in[5];
    const float* bu1 = (const float*)d_in[6];
    const float* Wu2 = (const float*)d_in[7];
    const float* bu2 = (const float*)d_in[8];
    const float* rw  = (const float*)d_in[9];
    float* out = (float*)d_out;

    const int B = in_sizes[0] / (64 * 32);
    agn_mfma<<<B / NBATCH, 256, 0, stream>>>(x, Wm1, bm1, Wm2, bm2, Wu1, bu1, Wu2, bu2, rw, out);
}

// Round 4
// 117.743 us; speedup vs baseline: 1.5800x; 1.5800x over previous
//
#include <hip/hip_runtime.h>
#include <hip/hip_bf16.h>

// AdaptiveGraphNetwork via MFMA 16x16x32 bf16. B=4096, N=64, D=32, H=64.
//
// v4: revert v3's occupancy push (launch_bounds(256,4) forced VGPR 128->64,
// spilling the ~96-VGPR weight-fragment set to scratch: FETCH 17->168MB,
// WRITE 34->113MB, kernel 40->98us). Back to NBATCH=8/NBI=2/LB(256,2),
// weights in registers. New in v4:
//  * sX: x staged in LDS once per iteration (coalesced 64B/lane loads,
//    padded stride 36 f32). Phase A dst/src gathers, phase C x, phase D
//    residual all read LDS instead of 4 global passes.
//  * Phase D swapped (out^T = Wu2^T @ hu^T, same B4 frags, same sH reads):
//    feature-contiguous C-frag -> residual ds_read_b128 + full-line
//    global_store_dwordx4 (was 8 scalar dword stores per lane).
// Kept from v2: swapped A/B/C with packed b64 LDS writes; wave-local
// lgkmcnt fences for A->B and C->D; lgkmcnt-only cross-wave barriers.
//
// Fragment maps (m89/m91-verified): A[m=lane&15][k=quad*8+j],
// B[k=quad*8+j][n=lane&15], C/D[row=quad*4+reg][col=lane&15].
// A-frag of W^T == B-frag of W: one fragment set serves both orientations.

typedef __bf16 bf16x8 __attribute__((ext_vector_type(8)));
typedef float  f32x4  __attribute__((ext_vector_type(4)));
typedef unsigned short u16;

#define NBATCH 8
#define NBI 2
#define ITERS (NBATCH / NBI)
#define HS  72   // sH row stride in u16 (144 B, 16B-aligned)
#define MBS 40   // sMB row stride in u16 (80 B, 16B-aligned)
#define XS  36   // sX row stride in f32 (144 B, 16B-aligned; 2-way banks max)

__device__ __forceinline__ u16 f2b(float f) { return __builtin_bit_cast(u16, (__bf16)f); }
__device__ __forceinline__ f32x4 MFMA(bf16x8 a, bf16x8 b, f32x4 c) {
    return __builtin_amdgcn_mfma_f32_16x16x32_bf16(a, b, c, 0, 0, 0);
}
__device__ __forceinline__ bf16x8 pack8(float4 a, float4 b) {
    bf16x8 r = {(__bf16)a.x, (__bf16)a.y, (__bf16)a.z, (__bf16)a.w,
                (__bf16)b.x, (__bf16)b.y, (__bf16)b.z, (__bf16)b.w};
    return r;
}
__device__ __forceinline__ uint2 relu_pack4(f32x4 acc, f32x4 bias) {
    uint2 o;
    o.x = (unsigned)f2b(fmaxf(acc[0] + bias[0], 0.f)) |
          ((unsigned)f2b(fmaxf(acc[1] + bias[1], 0.f)) << 16);
    o.y = (unsigned)f2b(fmaxf(acc[2] + bias[2], 0.f)) |
          ((unsigned)f2b(fmaxf(acc[3] + bias[3], 0.f)) << 16);
    return o;
}
// Wave-local LDS producer->consumer fence (same-wave ds ops are in-order).
__device__ __forceinline__ void wave_lds_fence() {
    asm volatile("s_waitcnt lgkmcnt(0)" ::: "memory");
}
// Cross-wave barrier draining LDS only (no cross-wave global deps).
__device__ __forceinline__ void barrier_lds() {
    asm volatile("s_waitcnt lgkmcnt(0)" ::: "memory");
    __builtin_amdgcn_s_barrier();
    asm volatile("" ::: "memory");
}

__global__ __launch_bounds__(256, 2)
void agn_mfma(const float* __restrict__ x, const float* __restrict__ Wm1,
              const float* __restrict__ bm1, const float* __restrict__ Wm2,
              const float* __restrict__ bm2, const float* __restrict__ Wu1,
              const float* __restrict__ bu1, const float* __restrict__ Wu2,
              const float* __restrict__ bu2, const float* __restrict__ rw_p,
              float* __restrict__ out)
{
    __shared__ __align__(16) u16   sH[256 * HS];   // 36864 B: edge-h rows 0..255; hu rows 0..127
    __shared__ __align__(16) u16   sMB[256 * MBS]; // 20480 B: edge messages
    __shared__ __align__(16) float sX[128 * XS];   // 18432 B: staged x (2 batches)

    const int t = threadIdx.x;
    const int w = t >> 6;
    const int lane = t & 63;
    const int ln = lane & 15;
    const int q  = lane >> 4;

    // ---------------- weight fragments (once per WG) ----------------
    bf16x8 B1a[4], B1b[4], B2[2][2], B3[2][4], B4[2][2];
#pragma unroll
    for (int nt = 0; nt < 4; ++nt)
#pragma unroll
        for (int j = 0; j < 8; ++j) {
            B1a[nt][j] = (__bf16)Wm1[(q * 8 + j) * 64 + nt * 16 + ln];
            B1b[nt][j] = (__bf16)Wm1[(32 + q * 8 + j) * 64 + nt * 16 + ln];
        }
#pragma unroll
    for (int s = 0; s < 2; ++s)
#pragma unroll
        for (int nt = 0; nt < 2; ++nt)
#pragma unroll
            for (int j = 0; j < 8; ++j)
                B2[s][nt][j] = (__bf16)Wm2[(s * 32 + q * 8 + j) * 32 + nt * 16 + ln];
#pragma unroll
    for (int s = 0; s < 2; ++s)
#pragma unroll
        for (int nt = 0; nt < 4; ++nt)
#pragma unroll
            for (int j = 0; j < 8; ++j)
                B3[s][nt][j] = (__bf16)Wu1[(s * 32 + q * 8 + j) * 64 + nt * 16 + ln];
#pragma unroll
    for (int s = 0; s < 2; ++s)
#pragma unroll
        for (int nt = 0; nt < 2; ++nt)
#pragma unroll
            for (int j = 0; j < 8; ++j)
                B4[s][nt][j] = (__bf16)Wu2[(s * 32 + q * 8 + j) * 32 + nt * 16 + ln];

    // Biases. Swapped phases index by C^T row = tile*16 + q*4 + r.
    f32x4 bm1s[4], bu1s[4], bm2s[2], bu2s[2];
#pragma unroll
    for (int ht = 0; ht < 4; ++ht)
#pragma unroll
        for (int r = 0; r < 4; ++r) {
            bm1s[ht][r] = bm1[ht * 16 + q * 4 + r];
            bu1s[ht][r] = bu1[ht * 16 + q * 4 + r];
        }
#pragma unroll
    for (int s = 0; s < 2; ++s)
#pragma unroll
        for (int r = 0; r < 4; ++r) {
            bm2s[s][r] = bm2[s * 16 + q * 4 + r];
            bu2s[s][r] = bu2[s * 16 + q * 4 + r];
        }
    const float rw = rw_p[0];
    const float om = 1.f - rw;

    const size_t base = (size_t)blockIdx.x * (NBATCH * 64 * 32);

    for (int it = 0; it < ITERS; ++it) {
        const float* xit = x + base + (size_t)it * (NBI * 64 * 32);
        float*       oit = out + base + (size_t)it * (NBI * 64 * 32);

        // ===== Stage: x (128 rows x 32) -> sX, coalesced 64B per thread =====
        {
            const int row = t >> 1;
            const int cb  = (t & 1) * 16;
            const float* src = xit + row * 32 + cb;
            float* dstp = &sX[row * XS + cb];
            float4 v0 = *(const float4*)(src);
            float4 v1 = *(const float4*)(src + 4);
            float4 v2 = *(const float4*)(src + 8);
            float4 v3 = *(const float4*)(src + 12);
            *(float4*)(dstp)      = v0;
            *(float4*)(dstp + 4)  = v1;
            *(float4*)(dstp + 8)  = v2;
            *(float4*)(dstp + 12) = v3;
        }
        barrier_lds();  // stage -> A gather is cross-wave

        // ===== Phase A (swapped): h^T = Wm1t^T@xd^T + Wm1b^T@xs^T, relu =====
#pragma unroll
        for (int m = 0; m < 4; ++m) {
            const int erow = (4 * w + m) * 16 + ln;
            const int bb = erow >> 7;
            int e = erow & 127;
            if (e >= 126) e = 0;  // pad rows, never read downstream
            const int dst  = (e < 63) ? e : e - 62;
            const int srcn = (e < 63) ? e + 1 : e - 63;
            const float* pd = &sX[((bb << 6) + dst) * XS + q * 8];
            const float* ps = &sX[((bb << 6) + srcn) * XS + q * 8];
            float4 d0 = *(const float4*)pd;
            float4 d1 = *(const float4*)(pd + 4);
            float4 s0 = *(const float4*)ps;
            float4 s1 = *(const float4*)(ps + 4);
            bf16x8 Ad = pack8(d0, d1);
            bf16x8 As = pack8(s0, s1);
            u16* rowp = &sH[erow * HS];
#pragma unroll
            for (int ht = 0; ht < 4; ++ht) {
                f32x4 acc = {0.f, 0.f, 0.f, 0.f};
                acc = MFMA(B1a[ht], Ad, acc);
                acc = MFMA(B1b[ht], As, acc);
                *(uint2*)&rowp[ht * 16 + q * 4] = relu_pack4(acc, bm1s[ht]);
            }
        }
        wave_lds_fence();  // A->B wave-local (rows [64w,64w+64))

        // ===== Phase B (swapped): msgb^T = Wm2^T @ h^T, relu =====
#pragma unroll
        for (int m = 0; m < 4; ++m) {
            const int row = (4 * w + m) * 16 + ln;
            bf16x8 A0 = __builtin_bit_cast(bf16x8, *(const uint4*)&sH[row * HS + q * 8]);
            bf16x8 A1 = __builtin_bit_cast(bf16x8, *(const uint4*)&sH[row * HS + 32 + q * 8]);
#pragma unroll
            for (int s = 0; s < 2; ++s) {
                f32x4 acc = {0.f, 0.f, 0.f, 0.f};
                acc = MFMA(B2[0][s], A0, acc);
                acc = MFMA(B2[1][s], A1, acc);
                *(uint2*)&sMB[row * MBS + s * 16 + q * 4] = relu_pack4(acc, bm2s[s]);
            }
        }
        barrier_lds();  // sMB scatter in C is cross-wave

        // ===== Phase C (swapped): hu^T = Wu1^T @ [x | scatter(msgb)]^T, relu =====
#pragma unroll
        for (int m = 0; m < 2; ++m) {
            const int row = (2 * w + m) * 16 + ln;   // node row in 2-batch chunk
            const int bb = row >> 6;
            const int i2 = row & 63;
            const float* p = &sX[row * XS + q * 8];
            float4 a0 = *(const float4*)p;
            float4 a1 = *(const float4*)(p + 4);
            bf16x8 A0 = pack8(a0, a1);
            float mv[8] = {0.f, 0.f, 0.f, 0.f, 0.f, 0.f, 0.f, 0.f};
            if (i2 < 63) {  // forward edge i2 -> dst i2
                uint4 u = *(const uint4*)&sMB[((bb << 7) + i2) * MBS + q * 8];
                const unsigned* pu = (const unsigned*)&u;
#pragma unroll
                for (int h = 0; h < 4; ++h) {
                    mv[2 * h]     += __uint_as_float(pu[h] << 16);
                    mv[2 * h + 1] += __uint_as_float(pu[h] & 0xFFFF0000u);
                }
            }
            if (i2 > 0) {   // backward edge 62+i2 -> dst i2
                uint4 u = *(const uint4*)&sMB[((bb << 7) + 62 + i2) * MBS + q * 8];
                const unsigned* pu = (const unsigned*)&u;
#pragma unroll
                for (int h = 0; h < 4; ++h) {
                    mv[2 * h]     += __uint_as_float(pu[h] << 16);
                    mv[2 * h + 1] += __uint_as_float(pu[h] & 0xFFFF0000u);
                }
            }
            bf16x8 A1;
#pragma unroll
            for (int j = 0; j < 8; ++j) A1[j] = (__bf16)mv[j];
#pragma unroll
            for (int ht = 0; ht < 4; ++ht) {
                f32x4 acc = {0.f, 0.f, 0.f, 0.f};
                acc = MFMA(B3[0][ht], A0, acc);
                acc = MFMA(B3[1][ht], A1, acc);
                *(uint2*)&sH[row * HS + ht * 16 + q * 4] = relu_pack4(acc, bu1s[ht]);
            }
        }
        wave_lds_fence();  // C->D wave-local (rows [32w,32w+32))

        // ===== Phase D (swapped): out^T = Wu2^T @ hu^T; full-line stores =====
        // A-operand = B4[kslice][s] (same frags); B-operand = same sH reads as
        // the normal orientation. C^T[feat=s*16+q*4+r][node=row] -> per-lane
        // 4 contiguous floats: residual ds_read_b128 + global_store_dwordx4.
#pragma unroll
        for (int m = 0; m < 2; ++m) {
            const int row = (2 * w + m) * 16 + ln;   // node row
            bf16x8 A0 = __builtin_bit_cast(bf16x8, *(const uint4*)&sH[row * HS + q * 8]);
            bf16x8 A1 = __builtin_bit_cast(bf16x8, *(const uint4*)&sH[row * HS + 32 + q * 8]);
#pragma unroll
            for (int s = 0; s < 2; ++s) {
                f32x4 acc = {0.f, 0.f, 0.f, 0.f};
                acc = MFMA(B4[0][s], A0, acc);
                acc = MFMA(B4[1][s], A1, acc);
                f32x4 xv = *(const f32x4*)&sX[row * XS + s * 16 + q * 4];
                float4 o;
                o.x = rw * (acc[0] + bu2s[s][0]) + om * xv[0];
                o.y = rw * (acc[1] + bu2s[s][1]) + om * xv[1];
                o.z = rw * (acc[2] + bu2s[s][2]) + om * xv[2];
                o.w = rw * (acc[3] + bu2s[s][3]) + om * xv[3];
                *(float4*)(oit + row * 32 + s * 16 + q * 4) = o;
            }
        }
        barrier_lds();  // sH/sMB/sX consumed before next iter overwrites
    }
}

extern "C" void kernel_launch(void* const* d_in, const int* in_sizes, int n_in,
                              void* d_out, int out_size, void* d_ws, size_t ws_size,
                              hipStream_t stream) {
    const float* x   = (const float*)d_in[0];
    const float* Wm1 = (const float*)d_in[1];
    const float* bm1 = (const float*)d_in[2];
    const float* Wm2 = (const float*)d_in[3];
    const float* bm2 = (const float*)d_in[4];
    const float* Wu1 = (const float*)d_in[5];
    const float* bu1 = (const float*)d_in[6];
    const float* Wu2 = (const float*)d_in[7];
    const float* bu2 = (const float*)d_in[8];
    const float* rw  = (const float*)d_in[9];
    float* out = (float*)d_out;

    const int B = in_sizes[0] / (64 * 32);
    agn_mfma<<<B / NBATCH, 256, 0, stream>>>(x, Wm1, bm1, Wm2, bm2, Wu1, bu1, Wu2, bu2, rw, out);
}